// Round 2
// baseline (237.123 us; speedup 1.0000x reference)
//
#include <hip/hip_runtime.h>

// Problem constants (fixed by the reference).
#define BB 4
#define SS 4096
#define DD 2048
#define D4 (DD / 4)        // 512 float4 channel-groups
#define CHUNK 16           // s-steps per thread
#define NCH (SS / CHUNK)   // 256 chunks per (b, d-column)

typedef float v4f __attribute__((ext_vector_type(4)));

// y[b,s,d] = bias[d] + sum_{k=0..3} x[b, s-3+k, d] * W[d,k]   (zero-pad s<0)
//
// Two-phase structure: issue ALL 19 chunk+halo loads first (memory-level
// parallelism: ~19 outstanding dwordx4 per wave), then compute + nt-store.
// VGPR ~110 -> 4 waves/SIMD; in-flight bytes/CU ~4.9 KB vs 2 KB for the
// interleaved R0 version (which measured 2.6 TB/s, latency-bound).
__global__ __launch_bounds__(256) void shortconv_kernel(
    const v4f* __restrict__ x,      // (B,S,D) as v4f over D
    const v4f* __restrict__ w4,     // (D,4): w4[d] = {W[d,0..3]}
    const v4f* __restrict__ bias4,  // (D/4)
    v4f* __restrict__ y)            // (B,S,D) as v4f over D
{
    const int t    = blockIdx.x * 256 + threadIdx.x;
    const int d4   = t & (D4 - 1);
    const int rest = t >> 9;            // / D4
    const int ch   = rest & (NCH - 1);  // uniform within a block
    const int b    = rest >> 8;         // / NCH

    const size_t base = ((size_t)b * SS + (size_t)(ch * CHUNK)) * D4 + (size_t)d4;

    // Weights/bias first: L2-hot after the first waves, retire before x loads.
    const v4f wr0 = w4[4 * d4 + 0];
    const v4f wr1 = w4[4 * d4 + 1];
    const v4f wr2 = w4[4 * d4 + 2];
    const v4f wr3 = w4[4 * d4 + 3];
    const v4f bv  = bias4[d4];

    // Phase 1: all loads. xs[0..2] = halo (x[s0-3..s0-1]), xs[3+i] = x[s0+i].
    v4f xs[CHUNK + 3];
    if (ch == 0) {
        xs[0] = (v4f)(0.f);
        xs[1] = (v4f)(0.f);
        xs[2] = (v4f)(0.f);
    } else {
        xs[0] = x[base - 3 * (size_t)D4];
        xs[1] = x[base - 2 * (size_t)D4];
        xs[2] = x[base - 1 * (size_t)D4];
    }
#pragma unroll
    for (int i = 0; i < CHUNK; ++i) {
        xs[3 + i] = x[base + (size_t)i * D4];
    }

    // Keep the load cluster at the top — don't let the scheduler re-sink
    // loads down between the stores (that's what capped R0 at 2.6 TB/s).
    __builtin_amdgcn_sched_barrier(0);

    // Phase 2: compute + streaming stores (output is write-once; nt keeps
    // the input resident in L2/L3 for halo reuse).
#pragma unroll
    for (int i = 0; i < CHUNK; ++i) {
        const v4f x0 = xs[i + 0];
        const v4f x1 = xs[i + 1];
        const v4f x2 = xs[i + 2];
        const v4f x3 = xs[i + 3];
        v4f r;
        r.x = bv.x + wr0.x * x0.x + wr0.y * x1.x + wr0.z * x2.x + wr0.w * x3.x;
        r.y = bv.y + wr1.x * x0.y + wr1.y * x1.y + wr1.z * x2.y + wr1.w * x3.y;
        r.z = bv.z + wr2.x * x0.z + wr2.y * x1.z + wr2.z * x2.z + wr2.w * x3.z;
        r.w = bv.w + wr3.x * x0.w + wr3.y * x1.w + wr3.z * x2.w + wr3.w * x3.w;
        __builtin_nontemporal_store(r, &y[base + (size_t)i * D4]);
    }
}

extern "C" void kernel_launch(void* const* d_in, const int* in_sizes, int n_in,
                              void* d_out, int out_size, void* d_ws, size_t ws_size,
                              hipStream_t stream) {
    const float* x    = (const float*)d_in[0];  // (B,S,D) fp32
    const float* w    = (const float*)d_in[1];  // (D,1,K) fp32
    const float* bias = (const float*)d_in[2];  // (D,)   fp32
    float* out        = (float*)d_out;          // (B,S,D) fp32

    const int total_threads = BB * NCH * D4;    // 524288 threads = 8192 waves
    const int block = 256;
    const int grid  = total_threads / block;    // 2048

    shortconv_kernel<<<grid, block, 0, stream>>>(
        (const v4f*)x, (const v4f*)w, (const v4f*)bias, (v4f*)out);
}

// Round 3
// 236.500 us; speedup vs baseline: 1.0026x; 1.0026x over previous
//
#include <hip/hip_runtime.h>

// Problem constants (fixed by the reference).
#define BB 4
#define SS 4096
#define DD 2048
#define D4 (DD / 4)        // 512 float4 channel-groups
#define CHUNK 32           // s-steps per thread
#define NCH (SS / CHUNK)   // 128 chunks per (b, d-column)
#define NBLK (BB * NCH * D4 / 256)  // 1024 blocks
#define PF 4               // prefetch ring depth

typedef float v4f __attribute__((ext_vector_type(4)));

// y[b,s,d] = bias[d] + sum_{k=0..3} x[b, s-3+k, d] * W[d,k]   (zero-pad s<0)
//
// R2 structure: copy-kernel mimicry. 4096 waves (16/CU), each walking 32
// s-steps linearly with a 4-deep prefetch ring (steady 1 load + 1 store per
// iteration). R0/R1 both capped at 2.6 TB/s with 8192 bursty one-shot waves;
// theory is request-stream entropy, so fewer/longer/linear streams.
__global__ __launch_bounds__(256) void shortconv_kernel(
    const v4f* __restrict__ x,      // (B,S,D) as v4f over D
    const v4f* __restrict__ w4,     // (D,4): w4[d] = {W[d,0..3]}
    const v4f* __restrict__ bias4,  // (D/4)
    v4f* __restrict__ y)            // (B,S,D) as v4f over D
{
    // XCD swizzle: round-robin dispatch (blk % 8 = XCD) -> give XCD j the
    // contiguous logical range [j*NBLK/8, (j+1)*NBLK/8) for L2 locality.
    const int logical = (blockIdx.x & 7) * (NBLK / 8) + (blockIdx.x >> 3);
    const int t    = logical * 256 + (int)threadIdx.x;
    const int d4   = t & (D4 - 1);
    const int rest = t >> 9;             // / D4
    const int ch   = rest & (NCH - 1);
    const int b    = rest >> 7;          // / NCH

    const v4f wr0 = w4[4 * d4 + 0];
    const v4f wr1 = w4[4 * d4 + 1];
    const v4f wr2 = w4[4 * d4 + 2];
    const v4f wr3 = w4[4 * d4 + 3];
    const v4f bv  = bias4[d4];

    const size_t base = ((size_t)b * SS + (size_t)(ch * CHUNK)) * D4 + (size_t)d4;

    // Sliding halo window: x[s-3], x[s-2], x[s-1].
    v4f h0, h1, h2;
    if (ch == 0) {
        h0 = (v4f)(0.f);
        h1 = (v4f)(0.f);
        h2 = (v4f)(0.f);
    } else {
        h0 = x[base - 3 * (size_t)D4];
        h1 = x[base - 2 * (size_t)D4];
        h2 = x[base - 1 * (size_t)D4];
    }

    // Prime the prefetch ring.
    v4f pf[PF];
#pragma unroll
    for (int i = 0; i < PF; ++i) pf[i] = x[base + (size_t)i * D4];

#pragma unroll
    for (int i = 0; i < CHUNK; ++i) {
        const v4f x3 = pf[i & (PF - 1)];
        if (i + PF < CHUNK) {
            pf[i & (PF - 1)] = x[base + (size_t)(i + PF) * D4];
        }
        v4f r;
        r.x = bv.x + wr0.x * h0.x + wr0.y * h1.x + wr0.z * h2.x + wr0.w * x3.x;
        r.y = bv.y + wr1.x * h0.y + wr1.y * h1.y + wr1.z * h2.y + wr1.w * x3.y;
        r.z = bv.z + wr2.x * h0.z + wr2.y * h1.z + wr2.z * h2.z + wr2.w * x3.z;
        r.w = bv.w + wr3.x * h0.w + wr3.y * h1.w + wr3.z * h2.w + wr3.w * x3.w;
        __builtin_nontemporal_store(r, &y[base + (size_t)i * D4]);
        h0 = h1;
        h1 = h2;
        h2 = x3;
    }
}

extern "C" void kernel_launch(void* const* d_in, const int* in_sizes, int n_in,
                              void* d_out, int out_size, void* d_ws, size_t ws_size,
                              hipStream_t stream) {
    const float* x    = (const float*)d_in[0];  // (B,S,D) fp32
    const float* w    = (const float*)d_in[1];  // (D,1,K) fp32
    const float* bias = (const float*)d_in[2];  // (D,)   fp32
    float* out        = (float*)d_out;          // (B,S,D) fp32

    shortconv_kernel<<<NBLK, 256, 0, stream>>>(
        (const v4f*)x, (const v4f*)w, (const v4f*)bias, (v4f*)out);
}